// Round 8
// baseline (49.611 us; speedup 1.0000x reference)
//
#include <hip/hip_runtime.h>
#include <math.h>

#define THREADS   256
#define R_OUTER   16
#define TILE      (THREADS * R_OUTER)   // 4096 outer points per block
#define MAX_STAGE 1024                  // inner points staged per pass (12 KB LDS)
#define NSPLIT    128

__device__ __forceinline__ float min3f(float a, float b, float c) {
    float d;
    asm("v_min3_f32 %0, %1, %2, %3" : "=v"(d) : "v"(a), "v"(b), "v"(c));
    return d;
}

// init per-point min slots to +huge (float bits, atomicMin(int) folds them)
__global__ __launch_bounds__(256) void chamfer_init(int* __restrict__ w, int n) {
    const int i = blockIdx.x * 256 + threadIdx.x;
    if (i < n) w[i] = __float_as_int(3.0e38f);
}

// min_j |p - q_j|^2 = |p|^2 + min_j (c_j + a_j*px + b_j*py),
// a = -2 qx, b = -2 qy, c = qx^2 + qy^2 (staged in LDS SoA, broadcast reads).
// SCALAR v_fma_f32 (full-rate, 2cyc) + v_min3_f32: 5 cyc/pair floor.
// Split results folded with atomicMin on int-viewed non-negative floats.
__global__ __launch_bounds__(THREADS) void chamfer_main(
    const float2* __restrict__ p, int n_p,
    const float2* __restrict__ q, int n_q,
    int nsplit, int* __restrict__ ws_min)   // [n_p + n_q] float-as-int
{
    const int side = blockIdx.z;
    const float2* __restrict__ outer = side ? q : p;
    const float2* __restrict__ inner = side ? p : q;
    const int n_outer = side ? n_q : n_p;
    const int n_inner = side ? n_p : n_q;
    int* __restrict__ wbase = ws_min + (side ? n_p : 0);

    const int tile = blockIdx.x;
    if (tile * TILE >= n_outer) return;          // uniform whole-block OOB
    const int split = blockIdx.y;
    const int tid   = threadIdx.x;

    // this split's inner range (chunk multiple of 4; splits may overlap-pad)
    const int chunk = ((n_inner + nsplit - 1) / nsplit + 3) & ~3;
    const int jlo   = split * chunk;

    // R_OUTER outer points per thread
    float px[R_OUTER], py[R_OUTER], m0[R_OUTER], m1[R_OUTER];
    #pragma unroll
    for (int r = 0; r < R_OUTER; ++r) {
        const int idx = tile * TILE + r * THREADS + tid;
        float2 pp = (idx < n_outer) ? outer[idx] : make_float2(0.f, 0.f);
        px[r] = pp.x; py[r] = pp.y;
        m0[r] = 3.0e38f; m1[r] = 3.0e38f;
    }

    __shared__ __align__(16) float sA[MAX_STAGE];
    __shared__ __align__(16) float sB[MAX_STAGE];
    __shared__ __align__(16) float sC[MAX_STAGE];

    for (int base = jlo; base < jlo + chunk; base += MAX_STAGE) {
        const int len = min(MAX_STAGE, jlo + chunk - base);   // multiple of 4

        // stage: 2 points per thread-iteration, float2 LDS writes
        for (int k = tid; k < (len >> 1); k += THREADS) {
            const int pt = base + (k << 1);
            float x0, y0, x1, y1; int v0, v1;
            if (pt + 1 < n_inner) {
                float4 v = *(const float4*)&inner[pt];
                x0 = v.x; y0 = v.y; x1 = v.z; y1 = v.w; v0 = v1 = 1;
            } else if (pt < n_inner) {
                float2 a = inner[pt];
                x0 = a.x; y0 = a.y; x1 = 0.f; y1 = 0.f; v0 = 1; v1 = 0;
            } else {
                x0 = y0 = x1 = y1 = 0.f; v0 = v1 = 0;
            }
            *(float2*)&sA[k << 1] = make_float2(-2.f * x0, -2.f * x1);
            *(float2*)&sB[k << 1] = make_float2(-2.f * y0, -2.f * y1);
            *(float2*)&sC[k << 1] = make_float2(
                v0 ? fmaf(x0, x0, y0 * y0) : 3.0e37f,
                v1 ? fmaf(x1, x1, y1 * y1) : 3.0e37f);
        }
        __syncthreads();

        const int n4 = len >> 2;
        for (int k4 = 0; k4 < n4; ++k4) {
            float4 A = ((const float4*)sA)[k4];   // uniform addr -> broadcast
            float4 B = ((const float4*)sB)[k4];
            float4 C = ((const float4*)sC)[k4];
            #pragma unroll
            for (int r = 0; r < R_OUTER; ++r) {
                float t0 = fmaf(A.x, px[r], fmaf(B.x, py[r], C.x));
                float t1 = fmaf(A.y, px[r], fmaf(B.y, py[r], C.y));
                float t2 = fmaf(A.z, px[r], fmaf(B.z, py[r], C.z));
                float t3 = fmaf(A.w, px[r], fmaf(B.w, py[r], C.w));
                m0[r] = min3f(m0[r], t0, t1);
                m1[r] = min3f(m1[r], t2, t3);
            }
        }
        __syncthreads();
    }

    // epilogue: add |p|^2, fold across splits (fire-and-forget atomics)
    #pragma unroll
    for (int r = 0; r < R_OUTER; ++r) {
        const int idx = tile * TILE + r * THREADS + tid;
        if (idx < n_outer) {
            const float hp = fmaf(px[r], px[r], py[r] * py[r]);
            const float v  = fminf(m0[r], m1[r]) + hp;
            atomicMin(&wbase[idx], __float_as_int(v));
        }
    }
}

// per-point sqrt + block partial sums
__global__ __launch_bounds__(256) void chamfer_reduce(
    const int* __restrict__ ws_min, int total_pts,
    float* __restrict__ block_sums)
{
    const int i = blockIdx.x * 256 + threadIdx.x;
    float d = 0.f;
    if (i < total_pts) {
        float mv = __int_as_float(ws_min[i]);
        d = sqrtf(fmaxf(mv, 0.f));
    }
    #pragma unroll
    for (int off = 32; off > 0; off >>= 1) d += __shfl_down(d, off);
    __shared__ float s[4];
    if ((threadIdx.x & 63) == 0) s[threadIdx.x >> 6] = d;
    __syncthreads();
    if (threadIdx.x == 0) block_sums[blockIdx.x] = (s[0] + s[1]) + (s[2] + s[3]);
}

__global__ __launch_bounds__(256) void chamfer_final(
    const float* __restrict__ block_sums, int n, float* __restrict__ out)
{
    float d = 0.f;
    for (int k = threadIdx.x; k < n; k += 256) d += block_sums[k];
    #pragma unroll
    for (int off = 32; off > 0; off >>= 1) d += __shfl_down(d, off);
    __shared__ float s[4];
    if ((threadIdx.x & 63) == 0) s[threadIdx.x >> 6] = d;
    __syncthreads();
    if (threadIdx.x == 0) out[0] = (s[0] + s[1]) + (s[2] + s[3]);
}

extern "C" void kernel_launch(void* const* d_in, const int* in_sizes, int n_in,
                              void* d_out, int out_size, void* d_ws, size_t ws_size,
                              hipStream_t stream) {
    const float2* p = (const float2*)d_in[0];   // (16384, 2) f32
    const float2* q = (const float2*)d_in[1];   // (16384, 2) f32
    const int N = in_sizes[0] / 2;
    const int M = in_sizes[1] / 2;
    float* out = (float*)d_out;

    const int total = N + M;
    const int nb    = (total + 255) / 256;

    int*   wmin = (int*)d_ws;                   // total ints (float bits)
    float* bsum = (float*)d_ws + total;         // nb floats

    hipLaunchKernelGGL(chamfer_init, dim3(nb), dim3(256), 0, stream, wmin, total);

    const int nsplit = NSPLIT;
    const int tA = (N + TILE - 1) / TILE;
    const int tB = (M + TILE - 1) / TILE;
    dim3 g1(tA > tB ? tA : tB, nsplit, 2);
    hipLaunchKernelGGL(chamfer_main, g1, dim3(THREADS), 0, stream,
                       p, N, q, M, nsplit, wmin);

    hipLaunchKernelGGL(chamfer_reduce, dim3(nb), dim3(256), 0, stream,
                       wmin, total, bsum);
    hipLaunchKernelGGL(chamfer_final, dim3(1), dim3(256), 0, stream, bsum, nb, out);
}

// Round 9
// 49.280 us; speedup vs baseline: 1.0067x; 1.0067x over previous
//
#include <hip/hip_runtime.h>
#include <math.h>

#define THREADS   256
#define R_OUTER   16
#define TILE      (THREADS * R_OUTER)   // 4096 outer points per block
#define MAX_STAGE 1024                  // inner points staged per pass (12 KB LDS)
#define NSPLIT    128

__device__ __forceinline__ float min3f(float a, float b, float c) {
    float d;
    asm("v_min3_f32 %0, %1, %2, %3" : "=v"(d) : "v"(a), "v"(b), "v"(c));
    return d;
}

// init per-point min slots to +huge (float bits, atomicMin(int) folds them)
__global__ __launch_bounds__(256) void chamfer_init(int* __restrict__ w, int n) {
    const int i = blockIdx.x * 256 + threadIdx.x;
    if (i < n) w[i] = __float_as_int(3.0e38f);
}

// min_j |p - q_j|^2 = |p|^2 + min_j (c_j + a_j*px + b_j*py),
// a = -2 qx, b = -2 qy, c = qx^2 + qy^2 (staged in LDS SoA, broadcast reads).
// Scalar v_fma_f32 (full-rate) + v_min3_f32: 2.5 VALU instr/pair.
// launch_bounds(256,2): give the register allocator headroom (~256 VGPR cap)
// so the ~75-reg live set stays in VGPRs -- no AGPR spill traffic.
__global__ __launch_bounds__(THREADS, 2) void chamfer_main(
    const float2* __restrict__ p, int n_p,
    const float2* __restrict__ q, int n_q,
    int nsplit, int* __restrict__ ws_min)   // [n_p + n_q] float-as-int
{
    const int side = blockIdx.z;
    const float2* __restrict__ outer = side ? q : p;
    const float2* __restrict__ inner = side ? p : q;
    const int n_outer = side ? n_q : n_p;
    const int n_inner = side ? n_p : n_q;
    int* __restrict__ wbase = ws_min + (side ? n_p : 0);

    const int tile = blockIdx.x;
    if (tile * TILE >= n_outer) return;          // uniform whole-block OOB
    const int split = blockIdx.y;
    const int tid   = threadIdx.x;

    // this split's inner range (chunk multiple of 4; splits may overlap-pad)
    const int chunk = ((n_inner + nsplit - 1) / nsplit + 3) & ~3;
    const int jlo   = split * chunk;

    // R_OUTER outer points per thread, single min accumulator per point
    float px[R_OUTER], py[R_OUTER], m[R_OUTER];
    #pragma unroll
    for (int r = 0; r < R_OUTER; ++r) {
        const int idx = tile * TILE + r * THREADS + tid;
        float2 pp = (idx < n_outer) ? outer[idx] : make_float2(0.f, 0.f);
        px[r] = pp.x; py[r] = pp.y;
        m[r] = 3.0e38f;
    }

    __shared__ __align__(16) float sA[MAX_STAGE];
    __shared__ __align__(16) float sB[MAX_STAGE];
    __shared__ __align__(16) float sC[MAX_STAGE];

    for (int base = jlo; base < jlo + chunk; base += MAX_STAGE) {
        const int len = min(MAX_STAGE, jlo + chunk - base);   // multiple of 4

        // stage: 2 points per thread-iteration, float2 LDS writes
        for (int k = tid; k < (len >> 1); k += THREADS) {
            const int pt = base + (k << 1);
            float x0, y0, x1, y1; int v0, v1;
            if (pt + 1 < n_inner) {
                float4 v = *(const float4*)&inner[pt];
                x0 = v.x; y0 = v.y; x1 = v.z; y1 = v.w; v0 = v1 = 1;
            } else if (pt < n_inner) {
                float2 a = inner[pt];
                x0 = a.x; y0 = a.y; x1 = 0.f; y1 = 0.f; v0 = 1; v1 = 0;
            } else {
                x0 = y0 = x1 = y1 = 0.f; v0 = v1 = 0;
            }
            *(float2*)&sA[k << 1] = make_float2(-2.f * x0, -2.f * x1);
            *(float2*)&sB[k << 1] = make_float2(-2.f * y0, -2.f * y1);
            *(float2*)&sC[k << 1] = make_float2(
                v0 ? fmaf(x0, x0, y0 * y0) : 3.0e37f,
                v1 ? fmaf(x1, x1, y1 * y1) : 3.0e37f);
        }
        __syncthreads();

        const int n4 = len >> 2;
        for (int k4 = 0; k4 < n4; ++k4) {
            float4 A = ((const float4*)sA)[k4];   // uniform addr -> broadcast
            float4 B = ((const float4*)sB)[k4];
            float4 C = ((const float4*)sC)[k4];
            #pragma unroll
            for (int r = 0; r < R_OUTER; ++r) {
                float t0 = fmaf(A.x, px[r], fmaf(B.x, py[r], C.x));
                float t1 = fmaf(A.y, px[r], fmaf(B.y, py[r], C.y));
                float t2 = fmaf(A.z, px[r], fmaf(B.z, py[r], C.z));
                float t3 = fmaf(A.w, px[r], fmaf(B.w, py[r], C.w));
                m[r] = min3f(m[r], t0, t1);
                m[r] = min3f(m[r], t2, t3);
            }
        }
        __syncthreads();
    }

    // epilogue: add |p|^2, fold across splits (fire-and-forget atomics)
    #pragma unroll
    for (int r = 0; r < R_OUTER; ++r) {
        const int idx = tile * TILE + r * THREADS + tid;
        if (idx < n_outer) {
            const float hp = fmaf(px[r], px[r], py[r] * py[r]);
            const float v  = m[r] + hp;
            atomicMin(&wbase[idx], __float_as_int(v));
        }
    }
}

// per-point sqrt + block partial sums
__global__ __launch_bounds__(256) void chamfer_reduce(
    const int* __restrict__ ws_min, int total_pts,
    float* __restrict__ block_sums)
{
    const int i = blockIdx.x * 256 + threadIdx.x;
    float d = 0.f;
    if (i < total_pts) {
        float mv = __int_as_float(ws_min[i]);
        d = sqrtf(fmaxf(mv, 0.f));
    }
    #pragma unroll
    for (int off = 32; off > 0; off >>= 1) d += __shfl_down(d, off);
    __shared__ float s[4];
    if ((threadIdx.x & 63) == 0) s[threadIdx.x >> 6] = d;
    __syncthreads();
    if (threadIdx.x == 0) block_sums[blockIdx.x] = (s[0] + s[1]) + (s[2] + s[3]);
}

__global__ __launch_bounds__(256) void chamfer_final(
    const float* __restrict__ block_sums, int n, float* __restrict__ out)
{
    float d = 0.f;
    for (int k = threadIdx.x; k < n; k += 256) d += block_sums[k];
    #pragma unroll
    for (int off = 32; off > 0; off >>= 1) d += __shfl_down(d, off);
    __shared__ float s[4];
    if ((threadIdx.x & 63) == 0) s[threadIdx.x >> 6] = d;
    __syncthreads();
    if (threadIdx.x == 0) out[0] = (s[0] + s[1]) + (s[2] + s[3]);
}

extern "C" void kernel_launch(void* const* d_in, const int* in_sizes, int n_in,
                              void* d_out, int out_size, void* d_ws, size_t ws_size,
                              hipStream_t stream) {
    const float2* p = (const float2*)d_in[0];   // (16384, 2) f32
    const float2* q = (const float2*)d_in[1];   // (16384, 2) f32
    const int N = in_sizes[0] / 2;
    const int M = in_sizes[1] / 2;
    float* out = (float*)d_out;

    const int total = N + M;
    const int nb    = (total + 255) / 256;

    int*   wmin = (int*)d_ws;                   // total ints (float bits)
    float* bsum = (float*)d_ws + total;         // nb floats

    hipLaunchKernelGGL(chamfer_init, dim3(nb), dim3(256), 0, stream, wmin, total);

    const int nsplit = NSPLIT;
    const int tA = (N + TILE - 1) / TILE;
    const int tB = (M + TILE - 1) / TILE;
    dim3 g1(tA > tB ? tA : tB, nsplit, 2);
    hipLaunchKernelGGL(chamfer_main, g1, dim3(THREADS), 0, stream,
                       p, N, q, M, nsplit, wmin);

    hipLaunchKernelGGL(chamfer_reduce, dim3(nb), dim3(256), 0, stream,
                       wmin, total, bsum);
    hipLaunchKernelGGL(chamfer_final, dim3(1), dim3(256), 0, stream, bsum, nb, out);
}

// Round 11
// 48.445 us; speedup vs baseline: 1.0241x; 1.0172x over previous
//
#include <hip/hip_runtime.h>
#include <math.h>

#define THREADS   256
#define R_OUTER   12
#define TILE      (THREADS * R_OUTER)   // 3072 outer points per block
#define MAX_STAGE 1024                  // inner points staged per pass (12 KB LDS)
#define NSPLIT    128

__device__ __forceinline__ float min3f(float a, float b, float c) {
    float d;
    asm("v_min3_f32 %0, %1, %2, %3" : "=v"(d) : "v"(a), "v"(b), "v"(c));
    return d;
}

// init per-point min slots to +huge (float bits; atomicMin(int) folds them), zero out
__global__ __launch_bounds__(256) void chamfer_init(
    int* __restrict__ w, int n, float* __restrict__ out)
{
    const int i = blockIdx.x * 256 + threadIdx.x;
    if (i == 0) out[0] = 0.f;
    if (i < n) w[i] = __float_as_int(3.0e38f);
}

// min_j |p - q_j|^2 = |p|^2 + min_j (c_j + a_j*px + b_j*py),
// a = -2 qx, b = -2 qy, c = qx^2 + qy^2 (staged in LDS SoA, broadcast reads).
// Scalar v_fma_f32 (full-rate) + v_min3_f32: 2.5 VALU instr/pair.
// R_OUTER=12 keeps live set (~56 regs) inside the arch-VGPR budget the
// allocator actually grants (R8 evidence: plain launch_bounds -> 56) so the
// min/coord state stays out of AGPRs (no accvgpr shuttle instructions).
__global__ __launch_bounds__(THREADS) void chamfer_main(
    const float2* __restrict__ p, int n_p,
    const float2* __restrict__ q, int n_q,
    int nsplit, int* __restrict__ ws_min)   // [n_p + n_q] float-as-int
{
    const int side = blockIdx.z;
    const float2* __restrict__ outer = side ? q : p;
    const float2* __restrict__ inner = side ? p : q;
    const int n_outer = side ? n_q : n_p;
    const int n_inner = side ? n_p : n_q;
    int* __restrict__ wbase = ws_min + (side ? n_p : 0);

    const int tile = blockIdx.x;
    if (tile * TILE >= n_outer) return;          // uniform whole-block OOB
    const int split = blockIdx.y;
    const int tid   = threadIdx.x;

    // this split's inner range (chunk multiple of 4; splits may overlap-pad)
    const int chunk = ((n_inner + nsplit - 1) / nsplit + 3) & ~3;
    const int jlo   = split * chunk;

    // R_OUTER outer points per thread, single min accumulator per point
    float px[R_OUTER], py[R_OUTER], m[R_OUTER];
    #pragma unroll
    for (int r = 0; r < R_OUTER; ++r) {
        const int idx = tile * TILE + r * THREADS + tid;
        float2 pp = (idx < n_outer) ? outer[idx] : make_float2(0.f, 0.f);
        px[r] = pp.x; py[r] = pp.y;
        m[r] = 3.0e38f;
    }

    __shared__ __align__(16) float sA[MAX_STAGE];
    __shared__ __align__(16) float sB[MAX_STAGE];
    __shared__ __align__(16) float sC[MAX_STAGE];

    for (int base = jlo; base < jlo + chunk; base += MAX_STAGE) {
        const int len = min(MAX_STAGE, jlo + chunk - base);   // multiple of 4

        // stage: 2 points per thread-iteration, float2 LDS writes
        for (int k = tid; k < (len >> 1); k += THREADS) {
            const int pt = base + (k << 1);
            float x0, y0, x1, y1; int v0, v1;
            if (pt + 1 < n_inner) {
                float4 v = *(const float4*)&inner[pt];
                x0 = v.x; y0 = v.y; x1 = v.z; y1 = v.w; v0 = v1 = 1;
            } else if (pt < n_inner) {
                float2 a = inner[pt];
                x0 = a.x; y0 = a.y; x1 = 0.f; y1 = 0.f; v0 = 1; v1 = 0;
            } else {
                x0 = y0 = x1 = y1 = 0.f; v0 = v1 = 0;
            }
            *(float2*)&sA[k << 1] = make_float2(-2.f * x0, -2.f * x1);
            *(float2*)&sB[k << 1] = make_float2(-2.f * y0, -2.f * y1);
            *(float2*)&sC[k << 1] = make_float2(
                v0 ? fmaf(x0, x0, y0 * y0) : 3.0e37f,
                v1 ? fmaf(x1, x1, y1 * y1) : 3.0e37f);
        }
        __syncthreads();

        const int n4 = len >> 2;
        for (int k4 = 0; k4 < n4; ++k4) {
            float4 A = ((const float4*)sA)[k4];   // uniform addr -> broadcast
            float4 B = ((const float4*)sB)[k4];
            float4 C = ((const float4*)sC)[k4];
            #pragma unroll
            for (int r = 0; r < R_OUTER; ++r) {
                float t0 = fmaf(A.x, px[r], fmaf(B.x, py[r], C.x));
                float t1 = fmaf(A.y, px[r], fmaf(B.y, py[r], C.y));
                float t2 = fmaf(A.z, px[r], fmaf(B.z, py[r], C.z));
                float t3 = fmaf(A.w, px[r], fmaf(B.w, py[r], C.w));
                m[r] = min3f(m[r], t0, t1);
                m[r] = min3f(m[r], t2, t3);
            }
        }
        __syncthreads();
    }

    // epilogue: add |p|^2, fold across splits (fire-and-forget atomics).
    // v >= 0 mathematically, so int-viewed atomicMin == float min.
    #pragma unroll
    for (int r = 0; r < R_OUTER; ++r) {
        const int idx = tile * TILE + r * THREADS + tid;
        if (idx < n_outer) {
            const float hp = fmaf(px[r], px[r], py[r] * py[r]);
            const float v  = fmaxf(m[r] + hp, 0.f);
            atomicMin(&wbase[idx], __float_as_int(v));
        }
    }
}

// per-point sqrt + block sum + one atomicAdd per block into out[0]
__global__ __launch_bounds__(256) void chamfer_reduce(
    const int* __restrict__ ws_min, int total_pts, float* __restrict__ out)
{
    const int i = blockIdx.x * 256 + threadIdx.x;
    float d = 0.f;
    if (i < total_pts)
        d = sqrtf(fmaxf(__int_as_float(ws_min[i]), 0.f));
    #pragma unroll
    for (int off = 32; off > 0; off >>= 1) d += __shfl_down(d, off);
    __shared__ float s[4];
    if ((threadIdx.x & 63) == 0) s[threadIdx.x >> 6] = d;
    __syncthreads();
    if (threadIdx.x == 0)
        atomicAdd(out, (s[0] + s[1]) + (s[2] + s[3]));
}

extern "C" void kernel_launch(void* const* d_in, const int* in_sizes, int n_in,
                              void* d_out, int out_size, void* d_ws, size_t ws_size,
                              hipStream_t stream) {
    const float2* p = (const float2*)d_in[0];   // (16384, 2) f32
    const float2* q = (const float2*)d_in[1];   // (16384, 2) f32
    const int N = in_sizes[0] / 2;
    const int M = in_sizes[1] / 2;
    float* out = (float*)d_out;

    const int total = N + M;
    const int nb    = (total + 255) / 256;

    int* wmin = (int*)d_ws;                     // total ints (float bits)

    hipLaunchKernelGGL(chamfer_init, dim3(nb), dim3(256), 0, stream,
                       wmin, total, out);

    const int nsplit = NSPLIT;
    const int tA = (N + TILE - 1) / TILE;
    const int tB = (M + TILE - 1) / TILE;
    dim3 g1(tA > tB ? tA : tB, nsplit, 2);
    hipLaunchKernelGGL(chamfer_main, g1, dim3(THREADS), 0, stream,
                       p, N, q, M, nsplit, wmin);

    hipLaunchKernelGGL(chamfer_reduce, dim3(nb), dim3(256), 0, stream,
                       wmin, total, out);
}

// Round 12
// 36.317 us; speedup vs baseline: 1.3661x; 1.3339x over previous
//
#include <hip/hip_runtime.h>
#include <math.h>

#define GRID     64
#define NCELLS   (GRID * GRID)        // 4096 cells, 8x8 px each
#define INV_CELL 0.125f
#define CELLSZ   8.0f

__device__ __forceinline__ int clampi(int v, int lo, int hi) {
    return v < lo ? lo : (v > hi ? hi : v);
}
__device__ __forceinline__ void cell_of(float x, float y, int& cx, int& cy) {
    cx = clampi((int)(x * INV_CELL), 0, GRID - 1);
    cy = clampi((int)(y * INV_CELL), 0, GRID - 1);
}

// K1: histogram both sets (hists pre-zeroed by memset)
__global__ __launch_bounds__(256) void chamfer_hist(
    const float2* __restrict__ p, int np,
    const float2* __restrict__ q, int nq,
    int* __restrict__ histP, int* __restrict__ histQ)
{
    const int i = blockIdx.x * 256 + threadIdx.x;
    if (i < np) { float2 v = p[i]; int cx, cy; cell_of(v.x, v.y, cx, cy);
                  atomicAdd(&histP[cy * GRID + cx], 1); }
    if (i < nq) { float2 v = q[i]; int cx, cy; cell_of(v.x, v.y, cx, cy);
                  atomicAdd(&histQ[cy * GRID + cx], 1); }
}

// K2: exclusive scan of both histograms (single block, 256 thr x 16 cells),
// writes cell starts + scatter cursors; zeroes out[0].
__global__ __launch_bounds__(256) void chamfer_scan(
    const int* __restrict__ histP, const int* __restrict__ histQ,
    int* __restrict__ startP, int* __restrict__ startQ,
    int* __restrict__ curP, int* __restrict__ curQ,
    int np, int nq, float* __restrict__ out)
{
    __shared__ int ls[256];
    const int t = threadIdx.x;
    if (t == 0) out[0] = 0.f;

    // --- set P ---
    {
        const int base = t * 16;
        int loc[16], s = 0;
        #pragma unroll
        for (int k = 0; k < 16; ++k) { loc[k] = histP[base + k]; s += loc[k]; }
        ls[t] = s; __syncthreads();
        for (int off = 1; off < 256; off <<= 1) {
            int v = (t >= off) ? ls[t - off] : 0;
            __syncthreads();
            ls[t] += v;
            __syncthreads();
        }
        int ex = ls[t] - s;
        #pragma unroll
        for (int k = 0; k < 16; ++k) {
            startP[base + k] = ex; curP[base + k] = ex; ex += loc[k];
        }
        if (t == 0) startP[NCELLS] = np;
    }
    __syncthreads();
    // --- set Q ---
    {
        const int base = t * 16;
        int loc[16], s = 0;
        #pragma unroll
        for (int k = 0; k < 16; ++k) { loc[k] = histQ[base + k]; s += loc[k]; }
        ls[t] = s; __syncthreads();
        for (int off = 1; off < 256; off <<= 1) {
            int v = (t >= off) ? ls[t - off] : 0;
            __syncthreads();
            ls[t] += v;
            __syncthreads();
        }
        int ex = ls[t] - s;
        #pragma unroll
        for (int k = 0; k < 16; ++k) {
            startQ[base + k] = ex; curQ[base + k] = ex; ex += loc[k];
        }
        if (t == 0) startQ[NCELLS] = nq;
    }
}

// K3: scatter points into cell-sorted arrays
__global__ __launch_bounds__(256) void chamfer_scatter(
    const float2* __restrict__ p, int np,
    const float2* __restrict__ q, int nq,
    int* __restrict__ curP, int* __restrict__ curQ,
    float2* __restrict__ binP, float2* __restrict__ binQ)
{
    const int i = blockIdx.x * 256 + threadIdx.x;
    if (i < np) { float2 v = p[i]; int cx, cy; cell_of(v.x, v.y, cx, cy);
                  binP[atomicAdd(&curP[cy * GRID + cx], 1)] = v; }
    if (i < nq) { float2 v = q[i]; int cx, cy; cell_of(v.x, v.y, cx, cy);
                  binQ[atomicAdd(&curQ[cy * GRID + cx], 1)] = v; }
}

__device__ __forceinline__ float scan_cell(
    const float2* __restrict__ tb, const int* __restrict__ ts,
    int cx, int cy, float qx, float qy, float best)
{
    if ((unsigned)cx >= GRID || (unsigned)cy >= GRID) return best;
    const int c = cy * GRID + cx;
    const int s = ts[c], e = ts[c + 1];
    for (int k = s; k < e; ++k) {
        float2 v = tb[k];
        float dx = qx - v.x, dy = qy - v.y;
        best = fminf(best, fmaf(dx, dx, dy * dy));
    }
    return best;
}

// K4: exact NN via expanding ring search; queries in binned (cell-sorted)
// order so wave lanes share candidate cells. Bound: after ring r, any
// unsearched cell is > r*CELLSZ away  =>  stop when best <= (r*CELLSZ)^2.
__global__ __launch_bounds__(256) void chamfer_search(
    const float2* __restrict__ binP, int np,
    const float2* __restrict__ binQ, int nq,
    const int* __restrict__ startP, const int* __restrict__ startQ,
    float* __restrict__ out)
{
    const int i = blockIdx.x * 256 + threadIdx.x;
    const int total = np + nq;
    float d = 0.f;
    if (i < total) {
        const bool sideP = (i < np);
        const float2 qry = sideP ? binP[i] : binQ[i - np];
        const float2* __restrict__ tb = sideP ? binQ : binP;
        const int*    __restrict__ ts = sideP ? startQ : startP;
        int cx, cy; cell_of(qry.x, qry.y, cx, cy);
        float best = 3.0e38f;
        for (int r = 0; r <= 128; ++r) {
            if (r == 0) {
                best = scan_cell(tb, ts, cx, cy, qry.x, qry.y, best);
            } else {
                for (int x = cx - r; x <= cx + r; ++x) {
                    best = scan_cell(tb, ts, x, cy - r, qry.x, qry.y, best);
                    best = scan_cell(tb, ts, x, cy + r, qry.x, qry.y, best);
                }
                for (int y = cy - r + 1; y <= cy + r - 1; ++y) {
                    best = scan_cell(tb, ts, cx - r, y, qry.x, qry.y, best);
                    best = scan_cell(tb, ts, cx + r, y, qry.x, qry.y, best);
                }
            }
            const float bnd = (float)r * CELLSZ;
            if (best <= bnd * bnd) break;
        }
        d = sqrtf(fmaxf(best, 0.f));
    }
    #pragma unroll
    for (int off = 32; off > 0; off >>= 1) d += __shfl_down(d, off);
    __shared__ float s[4];
    if ((threadIdx.x & 63) == 0) s[threadIdx.x >> 6] = d;
    __syncthreads();
    if (threadIdx.x == 0)
        atomicAdd(out, (s[0] + s[1]) + (s[2] + s[3]));
}

extern "C" void kernel_launch(void* const* d_in, const int* in_sizes, int n_in,
                              void* d_out, int out_size, void* d_ws, size_t ws_size,
                              hipStream_t stream) {
    const float2* p = (const float2*)d_in[0];   // (16384, 2) f32
    const float2* q = (const float2*)d_in[1];   // (16384, 2) f32
    const int N = in_sizes[0] / 2;
    const int M = in_sizes[1] / 2;
    float* out = (float*)d_out;

    // ws layout (ints then float2s, all 8B-aligned by construction)
    int* histP  = (int*)d_ws;                   // NCELLS
    int* histQ  = histP + NCELLS;               // NCELLS
    int* startP = histQ + NCELLS;               // NCELLS+1
    int* startQ = startP + NCELLS + 1;          // NCELLS+1
    int* curP   = startQ + NCELLS + 1;          // NCELLS
    int* curQ   = curP + NCELLS;                // NCELLS
    float2* binP = (float2*)(curQ + NCELLS + 2);// N entries (pad to 8B align)
    float2* binQ = binP + N;                    // M entries

    // zero both histograms in one memset (contiguous)
    hipMemsetAsync(histP, 0, 2 * NCELLS * sizeof(int), stream);

    const int nbPQ = (max(N, M) + 255) / 256;
    hipLaunchKernelGGL(chamfer_hist, dim3(nbPQ), dim3(256), 0, stream,
                       p, N, q, M, histP, histQ);

    hipLaunchKernelGGL(chamfer_scan, dim3(1), dim3(256), 0, stream,
                       histP, histQ, startP, startQ, curP, curQ, N, M, out);

    hipLaunchKernelGGL(chamfer_scatter, dim3(nbPQ), dim3(256), 0, stream,
                       p, N, q, M, curP, curQ, binP, binQ);

    const int nbS = (N + M + 255) / 256;
    hipLaunchKernelGGL(chamfer_search, dim3(nbS), dim3(256), 0, stream,
                       binP, N, binQ, M, startP, startQ, out);
}

// Round 13
// 31.027 us; speedup vs baseline: 1.5990x; 1.1705x over previous
//
#include <hip/hip_runtime.h>
#include <math.h>

#define GRID     64
#define NCELLS   (GRID * GRID)        // 4096 cells, 8x8 px each
#define INV_CELL 0.125f
#define CELLSZ   8.0f

__device__ __forceinline__ int clampi(int v, int lo, int hi) {
    return v < lo ? lo : (v > hi ? hi : v);
}
__device__ __forceinline__ void cell_of(float x, float y, int& cx, int& cy) {
    cx = clampi((int)(x * INV_CELL), 0, GRID - 1);
    cy = clampi((int)(y * INV_CELL), 0, GRID - 1);
}

// K0: zero both histograms (replaces hipMemsetAsync fill node)
__global__ __launch_bounds__(256) void chamfer_zero(int* __restrict__ h) {
    h[blockIdx.x * 256 + threadIdx.x] = 0;   // grid sized exactly 2*NCELLS/256
}

// K1: histogram both sets
__global__ __launch_bounds__(256) void chamfer_hist(
    const float2* __restrict__ p, int np,
    const float2* __restrict__ q, int nq,
    int* __restrict__ histP, int* __restrict__ histQ)
{
    const int i = blockIdx.x * 256 + threadIdx.x;
    if (i < np) { float2 v = p[i]; int cx, cy; cell_of(v.x, v.y, cx, cy);
                  atomicAdd(&histP[cy * GRID + cx], 1); }
    if (i < nq) { float2 v = q[i]; int cx, cy; cell_of(v.x, v.y, cx, cy);
                  atomicAdd(&histQ[cy * GRID + cx], 1); }
}

// K2: exclusive scan (2 blocks: blockIdx 0 -> P, 1 -> Q); zeroes out[0]
__global__ __launch_bounds__(256) void chamfer_scan(
    const int* __restrict__ histP, const int* __restrict__ histQ,
    int* __restrict__ startP, int* __restrict__ startQ,
    int* __restrict__ curP, int* __restrict__ curQ,
    int np, int nq, float* __restrict__ out)
{
    const int t = threadIdx.x;
    const int side = blockIdx.x;
    const int* __restrict__ hist  = side ? histQ : histP;
    int* __restrict__ start = side ? startQ : startP;
    int* __restrict__ cur   = side ? curQ : curP;
    const int n = side ? nq : np;
    if (side == 0 && t == 0) out[0] = 0.f;

    __shared__ int ls[256];
    const int base = t * 16;
    int loc[16], s = 0;
    #pragma unroll
    for (int k = 0; k < 16; ++k) { loc[k] = hist[base + k]; s += loc[k]; }
    ls[t] = s; __syncthreads();
    for (int off = 1; off < 256; off <<= 1) {
        int v = (t >= off) ? ls[t - off] : 0;
        __syncthreads();
        ls[t] += v;
        __syncthreads();
    }
    int ex = ls[t] - s;
    #pragma unroll
    for (int k = 0; k < 16; ++k) {
        start[base + k] = ex; cur[base + k] = ex; ex += loc[k];
    }
    if (t == 0) start[NCELLS] = n;
}

// K3: scatter points into cell-sorted arrays
__global__ __launch_bounds__(256) void chamfer_scatter(
    const float2* __restrict__ p, int np,
    const float2* __restrict__ q, int nq,
    int* __restrict__ curP, int* __restrict__ curQ,
    float2* __restrict__ binP, float2* __restrict__ binQ)
{
    const int i = blockIdx.x * 256 + threadIdx.x;
    if (i < np) { float2 v = p[i]; int cx, cy; cell_of(v.x, v.y, cx, cy);
                  binP[atomicAdd(&curP[cy * GRID + cx], 1)] = v; }
    if (i < nq) { float2 v = q[i]; int cx, cy; cell_of(v.x, v.y, cx, cy);
                  binQ[atomicAdd(&curQ[cy * GRID + cx], 1)] = v; }
}

__device__ __forceinline__ float scan_range(
    const float2* __restrict__ tb, int s, int e,
    float qx, float qy, float best)
{
    for (int k = s; k < e; ++k) {
        float2 v = tb[k];
        float dx = qx - v.x, dy = qy - v.y;
        best = fminf(best, fmaf(dx, dx, dy * dy));
    }
    return best;
}

// K4: exact NN. Fast path: the 3x3 neighborhood = 3 CONTIGUOUS point ranges
// (cells in a row are adjacent in the binned array). After cheb ring r, any
// unscanned cell is > r*8 px away  =>  stop when best <= (8r)^2.
// 128-thr blocks -> 256 blocks = 1 per CU (latency-bound; max CU coverage).
__global__ __launch_bounds__(128) void chamfer_search(
    const float2* __restrict__ binP, int np,
    const float2* __restrict__ binQ, int nq,
    const int* __restrict__ startP, const int* __restrict__ startQ,
    float* __restrict__ out)
{
    const int i = blockIdx.x * 128 + threadIdx.x;
    const int total = np + nq;
    float d = 0.f;
    if (i < total) {
        const bool sideP = (i < np);
        const float2 qry = sideP ? binP[i] : binQ[i - np];
        const float2* __restrict__ tb = sideP ? binQ : binP;
        const int*    __restrict__ ts = sideP ? startQ : startP;
        int cx, cy; cell_of(qry.x, qry.y, cx, cy);
        float best = 3.0e38f;

        // fused 3x3 (rings 0+1): 3 contiguous ranges
        const int x0 = max(cx - 1, 0), x1 = min(cx + 1, GRID - 1);
        const int y0 = max(cy - 1, 0), y1 = min(cy + 1, GRID - 1);
        for (int y = y0; y <= y1; ++y) {
            const int rb = y * GRID;
            best = scan_range(tb, ts[rb + x0], ts[rb + x1 + 1],
                              qry.x, qry.y, best);
        }

        if (best > CELLSZ * CELLSZ) {       // rare: expand rings from r=2
            for (int r = 2; r < GRID; ++r) {
                const int xa = max(cx - r, 0), xb = min(cx + r, GRID - 1);
                const int yT = cy - r, yB = cy + r;
                if (yT >= 0)
                    best = scan_range(tb, ts[yT * GRID + xa],
                                      ts[yT * GRID + xb + 1], qry.x, qry.y, best);
                if (yB < GRID)
                    best = scan_range(tb, ts[yB * GRID + xa],
                                      ts[yB * GRID + xb + 1], qry.x, qry.y, best);
                const int ya = max(cy - r + 1, 0), yb = min(cy + r - 1, GRID - 1);
                for (int y = ya; y <= yb; ++y) {
                    if (cx - r >= 0) {
                        const int c = y * GRID + cx - r;
                        best = scan_range(tb, ts[c], ts[c + 1], qry.x, qry.y, best);
                    }
                    if (cx + r < GRID) {
                        const int c = y * GRID + cx + r;
                        best = scan_range(tb, ts[c], ts[c + 1], qry.x, qry.y, best);
                    }
                }
                const float bnd = (float)r * CELLSZ;
                if (best <= bnd * bnd) break;
            }
        }
        d = sqrtf(fmaxf(best, 0.f));
    }

    #pragma unroll
    for (int off = 32; off > 0; off >>= 1) d += __shfl_down(d, off);
    __shared__ float s[2];
    if ((threadIdx.x & 63) == 0) s[threadIdx.x >> 6] = d;
    __syncthreads();
    if (threadIdx.x == 0) atomicAdd(out, s[0] + s[1]);
}

extern "C" void kernel_launch(void* const* d_in, const int* in_sizes, int n_in,
                              void* d_out, int out_size, void* d_ws, size_t ws_size,
                              hipStream_t stream) {
    const float2* p = (const float2*)d_in[0];   // (16384, 2) f32
    const float2* q = (const float2*)d_in[1];   // (16384, 2) f32
    const int N = in_sizes[0] / 2;
    const int M = in_sizes[1] / 2;
    float* out = (float*)d_out;

    // ws layout
    int* histP  = (int*)d_ws;                   // NCELLS
    int* histQ  = histP + NCELLS;               // NCELLS
    int* startP = histQ + NCELLS;               // NCELLS+1
    int* startQ = startP + NCELLS + 1;          // NCELLS+1
    int* curP   = startQ + NCELLS + 1;          // NCELLS
    int* curQ   = curP + NCELLS;                // NCELLS
    float2* binP = (float2*)(curQ + NCELLS + 2);// N entries (8B aligned)
    float2* binQ = binP + N;                    // M entries

    hipLaunchKernelGGL(chamfer_zero, dim3(2 * NCELLS / 256), dim3(256), 0, stream,
                       histP);

    const int nbPQ = (max(N, M) + 255) / 256;
    hipLaunchKernelGGL(chamfer_hist, dim3(nbPQ), dim3(256), 0, stream,
                       p, N, q, M, histP, histQ);

    hipLaunchKernelGGL(chamfer_scan, dim3(2), dim3(256), 0, stream,
                       histP, histQ, startP, startQ, curP, curQ, N, M, out);

    hipLaunchKernelGGL(chamfer_scatter, dim3(nbPQ), dim3(256), 0, stream,
                       p, N, q, M, curP, curQ, binP, binQ);

    const int nbS = (N + M + 127) / 128;
    hipLaunchKernelGGL(chamfer_search, dim3(nbS), dim3(128), 0, stream,
                       binP, N, binQ, M, startP, startQ, out);
}